// Round 6
// baseline (375.553 us; speedup 1.0000x reference)
//
#include <hip/hip_runtime.h>
#include <hip/hip_bf16.h>

typedef unsigned short u16;
typedef unsigned int u32;
typedef __attribute__((ext_vector_type(8))) __bf16 bf16x8;
typedef __attribute__((ext_vector_type(4))) float f32x4;
typedef __attribute__((ext_vector_type(4))) u32 u32x4;
typedef __attribute__((ext_vector_type(4))) u16 u16x4;

#define LQ 1000   // sequence length
#define MM 8000   // B*L tokens
// D=1024, H=16, HD=64, BH=128

__device__ __forceinline__ u16 f2bf(float f){
  __bf16 h = (__bf16)f;
  return __builtin_bit_cast(u16, h);
}
// async global->LDS, 16B per lane; LDS dest = wave-uniform base + lane*16 (m104/m108)
__device__ __forceinline__ void async_copy16(const void* g, void* l){
  __builtin_amdgcn_global_load_lds((const __attribute__((address_space(1))) u32*)g,
                                   (__attribute__((address_space(3))) u32*)l, 16, 0, 0);
}

// ---------------- fp32 -> bf16 convert (4 elems/thread) ----------------
__global__ __launch_bounds__(256)
void kcvt(const float* __restrict__ src, u16* __restrict__ dst, long n){
  const long i = ((long)blockIdx.x * 256 + threadIdx.x) * 4;
  if (i + 3 >= n) {
    for (long j = i; j < n; j++) dst[j] = f2bf(src[j]);
    return;
  }
  const float4 v = *(const float4*)&src[i];
  u16x4 o; o.x = f2bf(v.x); o.y = f2bf(v.y); o.z = f2bf(v.z); o.w = f2bf(v.w);
  *(u16x4*)&dst[i] = o;
}

// ---------------- fp32 read, transpose, bf16 write; 32x32 tiles ----------------
__global__ __launch_bounds__(256)
void ktranspose_cvt(const float* __restrict__ src, u16* __restrict__ dst, int R, int C){
  __shared__ u16 tile[32][33];
  const int tx = threadIdx.x & 31, ty = threadIdx.x >> 5;   // 32 x 8
  const long bx = (long)blockIdx.x * 32, by = (long)blockIdx.y * 32;
  #pragma unroll
  for (int i = 0; i < 32; i += 8) tile[ty + i][tx] = f2bf(src[(by + ty + i) * C + bx + tx]);
  __syncthreads();
  #pragma unroll
  for (int i = 0; i < 32; i += 8) dst[(bx + ty + i) * R + by + tx] = tile[tx][ty + i];
}

// ---------------- m97-style GEMM: C[M,N] = A[M,1024] * BT[N,1024]^T + bias ----------------
// EPI==0: scatter bf16 into Q [BH,L,64], K [BH,L,64], VT [BH,64,L]
// EPI==1: OF[m*1024 + n] = fp32(acc + bias)   <-- d_out is FLOAT (reference returns fp32)
template<int EPI>
__global__ __launch_bounds__(256)
void gemm128(const u16* __restrict__ A, const u16* __restrict__ BT, const float* __restrict__ bias,
             u16* __restrict__ O0, u16* __restrict__ O1, u16* __restrict__ O2,
             float* __restrict__ OF)
{
  constexpr int K = 1024;
  __shared__ __align__(16) u16 As[128 * 32];
  __shared__ __align__(16) u16 Bs[128 * 32];
  const int t = threadIdx.x, lane = t & 63, wave = t >> 6;
  const int quad = lane >> 4, l15 = lane & 15;
  const int m0 = blockIdx.y * 128, n0 = blockIdx.x * 128;
  const int wm = (wave >> 1) * 64, wn = (wave & 1) * 64;

  f32x4 acc[4][4] = {};

  const int srow = t >> 2, scol = (t & 3) * 8;              // 4 lanes per 32-elem row
  const long aoff0 = (long)min(m0 + srow,      MM - 1) * K + scol;
  const long aoff1 = (long)min(m0 + srow + 64, MM - 1) * K + scol;
  const long boff0 = (long)(n0 + srow)      * K + scol;
  const long boff1 = (long)(n0 + srow + 64) * K + scol;
  char* AsB = (char*)As + wave * 1024;
  char* BsB = (char*)Bs + wave * 1024;

  for (int kt = 0; kt < K; kt += 32) {
    __syncthreads();
    async_copy16(A  + aoff0 + kt, AsB);
    async_copy16(A  + aoff1 + kt, AsB + 4096);
    async_copy16(BT + boff0 + kt, BsB);
    async_copy16(BT + boff1 + kt, BsB + 4096);
    __syncthreads();
    bf16x8 af[4], bfv[4];
    #pragma unroll
    for (int i = 0; i < 4; i++) af[i]  = *(const bf16x8*)&As[(wm + i * 16 + l15) * 32 + quad * 8];
    #pragma unroll
    for (int i = 0; i < 4; i++) bfv[i] = *(const bf16x8*)&Bs[(wn + i * 16 + l15) * 32 + quad * 8];
    #pragma unroll
    for (int mi = 0; mi < 4; mi++)
      #pragma unroll
      for (int ni = 0; ni < 4; ni++)
        acc[mi][ni] = __builtin_amdgcn_mfma_f32_16x16x32_bf16(af[mi], bfv[ni], acc[mi][ni], 0, 0, 0);
  }

  float bs[4]; int cols[4];
  #pragma unroll
  for (int ni = 0; ni < 4; ni++) { cols[ni] = n0 + wn + ni * 16 + l15; bs[ni] = bias[cols[ni]]; }

  #pragma unroll
  for (int mi = 0; mi < 4; mi++) {
    #pragma unroll
    for (int r = 0; r < 4; r++) {
      const int row = m0 + wm + mi * 16 + quad * 4 + r;   // C/D: row = quad*4+reg, col = lane&15 (m89)
      if (row >= MM) continue;
      if (EPI == 0) {
        const int b = row / 1000, l = row - b * 1000;
        #pragma unroll
        for (int ni = 0; ni < 4; ni++) {
          const u16 o = f2bf(acc[mi][ni][r] + bs[ni]);
          const int col = cols[ni];
          const int which = col >> 10, hh = (col >> 6) & 15, dd = col & 63;
          const int bh = b * 16 + hh;
          if      (which == 0) O0[((long)bh * LQ + l) * 64 + dd] = o;
          else if (which == 1) O1[((long)bh * LQ + l) * 64 + dd] = o;
          else                 O2[((long)bh * 64 + dd) * LQ + l] = o;   // V stored transposed per head
        }
      } else {
        #pragma unroll
        for (int ni = 0; ni < 4; ni++)
          OF[(long)row * 1024 + cols[ni]] = acc[mi][ni][r] + bs[ni];    // fp32 store
      }
    }
  }
}

// ---------------- flash attention: block = 64 q-rows (4 waves x 16), K-tiles of 32 ----------------
__global__ __launch_bounds__(256)
void attn_kernel(const u16* __restrict__ Qb, const u16* __restrict__ Kb,
                 const u16* __restrict__ VTb, u16* __restrict__ AO)
{
  __shared__ __align__(16) u16 Ks[32 * 72];      // K tile [key][d], +8 pad (stride 144B)
  __shared__ __align__(16) u16 Vt[64 * 40];      // V^T tile [d][key], +8 pad
  __shared__ __align__(16) u16 Ps[4][16 * 40];   // per-wave P round-trip, +8 pad
  const int t = threadIdx.x, lane = t & 63, wave = t >> 6;
  const int quad = lane >> 4, l15 = lane & 15;
  const int bh = blockIdx.y, q0 = blockIdx.x * 64;
  const u16* Q  = Qb  + (long)bh * LQ * 64;
  const u16* Kp = Kb  + (long)bh * LQ * 64;
  const u16* VT = VTb + (long)bh * 64 * LQ;

  // Q fragments straight from global (A-layout: m = lane&15, k = quad*8+j — m120)
  const int qbase = q0 + wave * 16;
  const int qra = min(qbase + l15, LQ - 1);
  const bf16x8 aq0 = *(const bf16x8*)&Q[(long)qra * 64 +      quad * 8];
  const bf16x8 aq1 = *(const bf16x8*)&Q[(long)qra * 64 + 32 + quad * 8];

  int qrow[4];
  #pragma unroll
  for (int r = 0; r < 4; r++) qrow[r] = qbase + quad * 4 + r;

  float m_i[4] = { -__builtin_inff(), -__builtin_inff(), -__builtin_inff(), -__builtin_inff() };
  float l_i[4] = { 0.f, 0.f, 0.f, 0.f };
  f32x4 o[4] = {};

  const int qmax = min(q0 + 64, LQ);
  const int nkt = (qmax + 31) >> 5;
  const float sscale = 0.18033688011112042f;     // (1/sqrt(64)) * log2(e)

  const int kj  = t >> 3, kg8 = (t & 7) * 8;     // K staging: 8 lanes x 16B per key row
  const int vd  = t >> 2, vjg8 = (t & 3) * 8;    // V staging

  for (int kk = 0; kk < nkt; ++kk) {
    const int k0 = kk * 32;
    __syncthreads();
    { // K tile: 32 keys x 64 d, plain VGPR round-trip into padded LDS
      const int row = min(k0 + kj, LQ - 1);
      const u32x4 kv = *(const u32x4*)&Kp[(long)row * 64 + kg8];
      *(u32x4*)&Ks[kj * 72 + kg8] = kv;
    }
    { // V^T tile: 64 d-rows x 32 keys (source rows are 2000B-strided)
      const int jcl = min(k0 + vjg8, LQ - 8);
      const u32* vp = (const u32*)&VT[(long)vd * LQ + jcl];
      u32x4 vv = { vp[0], vp[1], vp[2], vp[3] };
      *(u32x4*)&Vt[vd * 40 + vjg8] = vv;
    }
    __syncthreads();

    // S = Q K^T : B-frag lane needs K[key = l15(+16)][d = quad*8+j (+32)]
    const int kA = l15, kB = l15 + 16;
    const bf16x8 b00 = *(const bf16x8*)&Ks[kA * 72 +      quad * 8];
    const bf16x8 b01 = *(const bf16x8*)&Ks[kA * 72 + 32 + quad * 8];
    const bf16x8 b10 = *(const bf16x8*)&Ks[kB * 72 +      quad * 8];
    const bf16x8 b11 = *(const bf16x8*)&Ks[kB * 72 + 32 + quad * 8];
    const f32x4 z = {};
    f32x4 s0 = __builtin_amdgcn_mfma_f32_16x16x32_bf16(aq0, b00, z, 0, 0, 0);
    s0       = __builtin_amdgcn_mfma_f32_16x16x32_bf16(aq1, b01, s0, 0, 0, 0);
    f32x4 s1 = __builtin_amdgcn_mfma_f32_16x16x32_bf16(aq0, b10, z, 0, 0, 0);
    s1       = __builtin_amdgcn_mfma_f32_16x16x32_bf16(aq1, b11, s1, 0, 0, 0);

    const int key0 = k0 + l15, key1 = key0 + 16;
    float al[4];
    #pragma unroll
    for (int r = 0; r < 4; r++) {
      float a  = (key0 <= qrow[r]) ? s0[r] * sscale : -3.0e38f;
      float b2 = (key1 <= qrow[r]) ? s1[r] * sscale : -3.0e38f;
      float mr = fmaxf(a, b2);
      mr = fmaxf(mr, __shfl_xor(mr, 1));
      mr = fmaxf(mr, __shfl_xor(mr, 2));
      mr = fmaxf(mr, __shfl_xor(mr, 4));
      mr = fmaxf(mr, __shfl_xor(mr, 8));
      const float mn = fmaxf(m_i[r], mr);
      al[r] = __builtin_amdgcn_exp2f(m_i[r] - mn);
      m_i[r] = mn;
      const float p0 = __builtin_amdgcn_exp2f(a - mn);
      const float p1 = __builtin_amdgcn_exp2f(b2 - mn);
      float ps = p0 + p1;
      ps += __shfl_xor(ps, 1); ps += __shfl_xor(ps, 2);
      ps += __shfl_xor(ps, 4); ps += __shfl_xor(ps, 8);
      l_i[r] = l_i[r] * al[r] + ps;
      Ps[wave][(quad * 4 + r) * 40 + l15]      = f2bf(p0);   // C-layout -> LDS
      Ps[wave][(quad * 4 + r) * 40 + l15 + 16] = f2bf(p1);
    }
    #pragma unroll
    for (int c = 0; c < 4; c++) {
      f32x4 oc = o[c];
      oc[0] *= al[0]; oc[1] *= al[1]; oc[2] *= al[2]; oc[3] *= al[3];
      o[c] = oc;
    }
    __syncthreads();   // Ps writes visible before cross-lane A-frag read
    const bf16x8 ap = *(const bf16x8*)&Ps[wave][l15 * 40 + quad * 8];
    #pragma unroll
    for (int c = 0; c < 4; c++) {   // B-frag: V[key=quad*8+j][d=c*16+l15] = Vt row (c*16+l15)
      const bf16x8 bv = *(const bf16x8*)&Vt[(c * 16 + l15) * 40 + quad * 8];
      o[c] = __builtin_amdgcn_mfma_f32_16x16x32_bf16(ap, bv, o[c], 0, 0, 0);
    }
  }

  const int b = bh >> 4, h = bh & 15;
  #pragma unroll
  for (int r = 0; r < 4; r++) {
    if (qrow[r] >= LQ) continue;
    const float inv = 1.0f / l_i[r];
    const long base = ((long)(b * LQ + qrow[r])) * 1024 + h * 64 + l15;
    #pragma unroll
    for (int c = 0; c < 4; c++) AO[base + c * 16] = f2bf(o[c][r] * inv);
  }
}

// ---------------- launcher ----------------
extern "C" void kernel_launch(void* const* d_in, const int* in_sizes, int n_in,
                              void* d_out, int out_size, void* d_ws, size_t ws_size,
                              hipStream_t stream) {
  const float* x    = (const float*)d_in[0];   // [8,1000,1024] fp32
  const float* Wqkv = (const float*)d_in[1];   // [1024,3072]  fp32
  const float* bqkv = (const float*)d_in[2];   // [3072]       fp32
  const float* Wo   = (const float*)d_in[3];   // [1024,1024]  fp32
  const float* bo   = (const float*)d_in[4];   // [1024]       fp32
  float* out = (float*)d_out;                  // [8,1000,1024] fp32  <-- reference output dtype

  char* ws = (char*)d_ws;                      // same layout as rounds 2-5 (validated)
  u16* WqkvT = (u16*)(ws);                                   // 3072*1024*2 = 6291456
  u16* WoT   = (u16*)(ws + 6291456);                         // 1024*1024*2 = 2097152
  u16* xb    = (u16*)(ws + 8388608);                         // 8000*1024*2 = 16384000
  u16* Qb    = (u16*)(ws + 8388608 + 16384000L);             // 128*1000*64*2
  u16* Kb    = (u16*)(ws + 8388608 + 2 * 16384000L);
  u16* VTb   = (u16*)(ws + 8388608 + 3 * 16384000L);
  u16* AO    = xb;   // reuse: x fully consumed by gemm<0> before attn writes AO

  kcvt<<<8000, 256, 0, stream>>>(x, xb, 8192000L);
  ktranspose_cvt<<<dim3(96, 32), 256, 0, stream>>>(Wqkv, WqkvT, 1024, 3072);
  ktranspose_cvt<<<dim3(32, 32), 256, 0, stream>>>(Wo,   WoT,   1024, 1024);
  gemm128<0><<<dim3(24, 63), 256, 0, stream>>>(xb, WqkvT, bqkv, Qb, Kb, VTb, nullptr);
  attn_kernel<<<dim3(16, 128), 256, 0, stream>>>(Qb, Kb, VTb, AO);
  gemm128<1><<<dim3(8, 63), 256, 0, stream>>>(AO, WoT, bo, nullptr, nullptr, nullptr, out);
}

// Round 7
// 297.659 us; speedup vs baseline: 1.2617x; 1.2617x over previous
//
#include <hip/hip_runtime.h>
#include <hip/hip_bf16.h>

typedef unsigned short u16;
typedef unsigned int u32;
typedef __attribute__((ext_vector_type(8))) __bf16 bf16x8;
typedef __attribute__((ext_vector_type(4))) float f32x4;
typedef __attribute__((ext_vector_type(4))) u32 u32x4;
typedef __attribute__((ext_vector_type(4))) u16 u16x4;

#define LQ 1000   // sequence length
#define MM 8000   // B*L tokens
// D=1024, H=16, HD=64, BH=128

__device__ __forceinline__ u16 f2bf(float f){
  __bf16 h = (__bf16)f;
  return __builtin_bit_cast(u16, h);
}
// async global->LDS, 16B per lane; LDS dest = wave-uniform base + lane*16 (m104/m108)
__device__ __forceinline__ void async_copy16(const void* g, void* l){
  __builtin_amdgcn_global_load_lds((const __attribute__((address_space(1))) u32*)g,
                                   (__attribute__((address_space(3))) u32*)l, 16, 0, 0);
}

// ---------------- fp32 -> bf16 convert (4 elems/thread) ----------------
__global__ __launch_bounds__(256)
void kcvt(const float* __restrict__ src, u16* __restrict__ dst, long n){
  const long i = ((long)blockIdx.x * 256 + threadIdx.x) * 4;
  if (i + 3 >= n) {
    for (long j = i; j < n; j++) dst[j] = f2bf(src[j]);
    return;
  }
  const float4 v = *(const float4*)&src[i];
  u16x4 o; o.x = f2bf(v.x); o.y = f2bf(v.y); o.z = f2bf(v.z); o.w = f2bf(v.w);
  *(u16x4*)&dst[i] = o;
}

// ---------------- fp32 read, transpose, bf16 write; 32x32 tiles ----------------
__global__ __launch_bounds__(256)
void ktranspose_cvt(const float* __restrict__ src, u16* __restrict__ dst, int R, int C){
  __shared__ u16 tile[32][33];
  const int tx = threadIdx.x & 31, ty = threadIdx.x >> 5;   // 32 x 8
  const long bx = (long)blockIdx.x * 32, by = (long)blockIdx.y * 32;
  #pragma unroll
  for (int i = 0; i < 32; i += 8) tile[ty + i][tx] = f2bf(src[(by + ty + i) * C + bx + tx]);
  __syncthreads();
  #pragma unroll
  for (int i = 0; i < 32; i += 8) dst[(bx + ty + i) * R + by + tx] = tile[tx][ty + i];
}

// ---------------- m97-style GEMM: C[M,N] = A[M,1024] * BT[N,1024]^T + bias ----------------
// EPI==0: scatter bf16 into Q [BH,L,64], K [BH,L,64], VT [BH,64,L]
// EPI==1: OF[m*1024 + n] = fp32(acc + bias)
template<int EPI>
__global__ __launch_bounds__(256)
void gemm128(const u16* __restrict__ A, const u16* __restrict__ BT, const float* __restrict__ bias,
             u16* __restrict__ O0, u16* __restrict__ O1, u16* __restrict__ O2,
             float* __restrict__ OF)
{
  constexpr int K = 1024;
  __shared__ __align__(16) u16 As[128 * 32];
  __shared__ __align__(16) u16 Bs[128 * 32];
  const int t = threadIdx.x, lane = t & 63, wave = t >> 6;
  const int quad = lane >> 4, l15 = lane & 15;
  const int m0 = blockIdx.y * 128, n0 = blockIdx.x * 128;
  const int wm = (wave >> 1) * 64, wn = (wave & 1) * 64;

  f32x4 acc[4][4] = {};

  const int srow = t >> 2, scol = (t & 3) * 8;              // 4 lanes per 32-elem row
  const long aoff0 = (long)min(m0 + srow,      MM - 1) * K + scol;
  const long aoff1 = (long)min(m0 + srow + 64, MM - 1) * K + scol;
  const long boff0 = (long)(n0 + srow)      * K + scol;
  const long boff1 = (long)(n0 + srow + 64) * K + scol;
  char* AsB = (char*)As + wave * 1024;
  char* BsB = (char*)Bs + wave * 1024;

  for (int kt = 0; kt < K; kt += 32) {
    __syncthreads();
    async_copy16(A  + aoff0 + kt, AsB);
    async_copy16(A  + aoff1 + kt, AsB + 4096);
    async_copy16(BT + boff0 + kt, BsB);
    async_copy16(BT + boff1 + kt, BsB + 4096);
    __syncthreads();
    bf16x8 af[4], bfv[4];
    #pragma unroll
    for (int i = 0; i < 4; i++) af[i]  = *(const bf16x8*)&As[(wm + i * 16 + l15) * 32 + quad * 8];
    #pragma unroll
    for (int i = 0; i < 4; i++) bfv[i] = *(const bf16x8*)&Bs[(wn + i * 16 + l15) * 32 + quad * 8];
    #pragma unroll
    for (int mi = 0; mi < 4; mi++)
      #pragma unroll
      for (int ni = 0; ni < 4; ni++)
        acc[mi][ni] = __builtin_amdgcn_mfma_f32_16x16x32_bf16(af[mi], bfv[ni], acc[mi][ni], 0, 0, 0);
  }

  float bs[4]; int cols[4];
  #pragma unroll
  for (int ni = 0; ni < 4; ni++) { cols[ni] = n0 + wn + ni * 16 + l15; bs[ni] = bias[cols[ni]]; }

  #pragma unroll
  for (int mi = 0; mi < 4; mi++) {
    #pragma unroll
    for (int r = 0; r < 4; r++) {
      const int row = m0 + wm + mi * 16 + quad * 4 + r;   // C/D: row = quad*4+reg, col = lane&15 (m89)
      if (row >= MM) continue;
      if (EPI == 0) {
        const int b = row / 1000, l = row - b * 1000;
        #pragma unroll
        for (int ni = 0; ni < 4; ni++) {
          const u16 o = f2bf(acc[mi][ni][r] + bs[ni]);
          const int col = cols[ni];
          const int which = col >> 10, hh = (col >> 6) & 15, dd = col & 63;
          const int bh = b * 16 + hh;
          if      (which == 0) O0[((long)bh * LQ + l) * 64 + dd] = o;
          else if (which == 1) O1[((long)bh * LQ + l) * 64 + dd] = o;
          else                 O2[((long)bh * 64 + dd) * LQ + l] = o;   // V stored transposed per head
        }
      } else {
        #pragma unroll
        for (int ni = 0; ni < 4; ni++)
          OF[(long)row * 1024 + cols[ni]] = acc[mi][ni][r] + bs[ni];    // fp32 store
      }
    }
  }
}

// ---------------- flash attention v2: barrier-free, LDS-free K/V, S^T orientation ----------
// One wave owns 32 q-rows (2 column-blocks of 16). Grid: x = ceil(L/128), y = bh.
// S^T = K Q^T  (A=K, B=Q): C-layout rows = keys (quad*4+r), cols = q (l15)  [m89]
// O^T = V^T P^T (A=V^T, B=P^T): C rows = d, cols = q.
// Only LDS: per-wave P buffer for C-layout -> B-frag transform (same-wave, no barrier:
// proven by round2==round3 bit-identity on this compiler).
__global__ __launch_bounds__(256)
void attn_kernel(const u16* __restrict__ Qb, const u16* __restrict__ Kb,
                 const u16* __restrict__ VTb, u16* __restrict__ AO)
{
  __shared__ __align__(16) u16 Ps[4][2][16 * 40];   // [wave][qblock][q=16][key=32 +8 pad]
  const int t = threadIdx.x, lane = t & 63, wave = t >> 6;
  const int quad = lane >> 4, l15 = lane & 15;
  const int bh = blockIdx.y;
  const int qbase = blockIdx.x * 128 + wave * 32;   // multiple of 32
  if (qbase >= LQ) return;                          // wave-uniform, no barriers in kernel
  const u16* Q  = Qb  + (long)bh * LQ * 64;
  const u16* Kp = Kb  + (long)bh * LQ * 64;
  const u16* VT = VTb + (long)bh * 64 * LQ;

  // Q B-frags for the two q-blocks: B[k=d=quad*8+j][n=q=l15]
  int qv[2]; bf16x8 bq0[2], bq1[2];
  #pragma unroll
  for (int g = 0; g < 2; g++) {
    qv[g] = qbase + g * 16 + l15;                   // this lane's column
    const int qc = min(qv[g], LQ - 1);
    bq0[g] = *(const bf16x8*)&Q[(long)qc * 64 +      quad * 8];
    bq1[g] = *(const bf16x8*)&Q[(long)qc * 64 + 32 + quad * 8];
  }

  float m_i[2] = { -3.0e38f, -3.0e38f }, l_i[2] = { 0.f, 0.f };
  f32x4 o[2][4] = {};

  const float sscale = 0.18033688011112042f;        // (1/sqrt(64)) * log2(e)
  const int nkt = (min(qbase + 32, LQ) + 31) >> 5;  // k0max = qbase <= every valid column

  for (int kk = 0; kk < nkt; ++kk) {
    const int k0 = kk * 32;
    // K A-frags: A[m=key][k=d]; two key halves (l15, l15+16)
    const int krA = min(k0 + l15, LQ - 1), krB = min(k0 + 16 + l15, LQ - 1);
    const bf16x8 a00 = *(const bf16x8*)&Kp[(long)krA * 64 +      quad * 8];
    const bf16x8 a01 = *(const bf16x8*)&Kp[(long)krA * 64 + 32 + quad * 8];
    const bf16x8 a10 = *(const bf16x8*)&Kp[(long)krB * 64 +      quad * 8];
    const bf16x8 a11 = *(const bf16x8*)&Kp[(long)krB * 64 + 32 + quad * 8];
    // V^T A-frags (shared by both q-blocks): A[m=d=c*16+l15][k=key=quad*8+j]
    bf16x8 av[4];
    #pragma unroll
    for (int c = 0; c < 4; c++)
      av[c] = *(const bf16x8*)&VT[(long)(c * 16 + l15) * LQ + k0 + quad * 8];

    #pragma unroll
    for (int g = 0; g < 2; g++) {
      const f32x4 z = {};
      f32x4 s0 = __builtin_amdgcn_mfma_f32_16x16x32_bf16(a00, bq0[g], z, 0, 0, 0);
      s0       = __builtin_amdgcn_mfma_f32_16x16x32_bf16(a01, bq1[g], s0, 0, 0, 0);
      f32x4 s1 = __builtin_amdgcn_mfma_f32_16x16x32_bf16(a10, bq0[g], z, 0, 0, 0);
      s1       = __builtin_amdgcn_mfma_f32_16x16x32_bf16(a11, bq1[g], s1, 0, 0, 0);

      const int q = qv[g];
      float x0[4], x1[4], mloc = -3.0e38f;
      #pragma unroll
      for (int r = 0; r < 4; r++) {
        const int key0 = k0 + quad * 4 + r;         // S^T row = key (m89)
        x0[r] = (key0      <= q) ? s0[r] * sscale : -3.0e38f;
        x1[r] = (key0 + 16 <= q) ? s1[r] * sscale : -3.0e38f;
        mloc = fmaxf(mloc, fmaxf(x0[r], x1[r]));
      }
      mloc = fmaxf(mloc, __shfl_xor(mloc, 16));     // reduce across quads (cols fixed)
      mloc = fmaxf(mloc, __shfl_xor(mloc, 32));
      const float mn = fmaxf(m_i[g], mloc);         // finite: key k0 <= qbase <= q unmasked
      const float al = __builtin_amdgcn_exp2f(m_i[g] - mn);
      m_i[g] = mn;
      float ls = 0.f;
      u16x4 w0, w1;
      #pragma unroll
      for (int r = 0; r < 4; r++) {
        x0[r] = __builtin_amdgcn_exp2f(x0[r] - mn);
        x1[r] = __builtin_amdgcn_exp2f(x1[r] - mn);
        ls += x0[r] + x1[r];
        w0[r] = f2bf(x0[r]); w1[r] = f2bf(x1[r]);
      }
      ls += __shfl_xor(ls, 16);
      ls += __shfl_xor(ls, 32);
      l_i[g] = l_i[g] * al + ls;
      // P[q][key] -> per-wave LDS (row l15 written only by lanes with this l15)
      *(u16x4*)&Ps[wave][g][l15 * 40 + quad * 4]      = w0;
      *(u16x4*)&Ps[wave][g][l15 * 40 + 16 + quad * 4] = w1;
      #pragma unroll
      for (int c = 0; c < 4; c++) {
        f32x4 oc = o[g][c];
        oc[0] *= al; oc[1] *= al; oc[2] *= al; oc[3] *= al;
        o[g][c] = oc;
      }
      // B-frag of P^T: B[k=key=quad*8+j][n=q=l15] = P[l15][quad*8+j] (same-wave r/w)
      const bf16x8 bp = *(const bf16x8*)&Ps[wave][g][l15 * 40 + quad * 8];
      #pragma unroll
      for (int c = 0; c < 4; c++)
        o[g][c] = __builtin_amdgcn_mfma_f32_16x16x32_bf16(av[c], bp, o[g][c], 0, 0, 0);
    }
  }

  const int b = bh >> 4, h = bh & 15;
  #pragma unroll
  for (int g = 0; g < 2; g++) {
    if (qv[g] >= LQ) continue;
    const float inv = 1.0f / l_i[g];
    const long base = ((long)(b * LQ + qv[g])) * 1024 + h * 64;
    #pragma unroll
    for (int c = 0; c < 4; c++) {                   // O^T: row d = c*16+quad*4+r, col q
      u16x4 w;
      #pragma unroll
      for (int r = 0; r < 4; r++) w[r] = f2bf(o[g][c][r] * inv);
      *(u16x4*)&AO[base + c * 16 + quad * 4] = w;   // 8B store, d-contiguous
    }
  }
}

// ---------------- launcher ----------------
extern "C" void kernel_launch(void* const* d_in, const int* in_sizes, int n_in,
                              void* d_out, int out_size, void* d_ws, size_t ws_size,
                              hipStream_t stream) {
  const float* x    = (const float*)d_in[0];   // [8,1000,1024] fp32
  const float* Wqkv = (const float*)d_in[1];   // [1024,3072]  fp32
  const float* bqkv = (const float*)d_in[2];   // [3072]       fp32
  const float* Wo   = (const float*)d_in[3];   // [1024,1024]  fp32
  const float* bo   = (const float*)d_in[4];   // [1024]       fp32
  float* out = (float*)d_out;                  // [8,1000,1024] fp32

  char* ws = (char*)d_ws;                      // validated layout (rounds 2-6)
  u16* WqkvT = (u16*)(ws);                                   // 3072*1024*2 = 6291456
  u16* WoT   = (u16*)(ws + 6291456);                         // 1024*1024*2 = 2097152
  u16* xb    = (u16*)(ws + 8388608);                         // 8000*1024*2 = 16384000
  u16* Qb    = (u16*)(ws + 8388608 + 16384000L);             // 128*1000*64*2
  u16* Kb    = (u16*)(ws + 8388608 + 2 * 16384000L);
  u16* VTb   = (u16*)(ws + 8388608 + 3 * 16384000L);
  u16* AO    = xb;   // reuse: x fully consumed by gemm<0> before attn writes AO

  kcvt<<<8000, 256, 0, stream>>>(x, xb, 8192000L);
  ktranspose_cvt<<<dim3(96, 32), 256, 0, stream>>>(Wqkv, WqkvT, 1024, 3072);
  ktranspose_cvt<<<dim3(32, 32), 256, 0, stream>>>(Wo,   WoT,   1024, 1024);
  gemm128<0><<<dim3(24, 63), 256, 0, stream>>>(xb, WqkvT, bqkv, Qb, Kb, VTb, nullptr);
  attn_kernel<<<dim3(8, 128), 256, 0, stream>>>(Qb, Kb, VTb, AO);
  gemm128<1><<<dim3(8, 63), 256, 0, stream>>>(AO, WoT, bo, nullptr, nullptr, nullptr, out);
}